// Round 5
// baseline (439.900 us; speedup 1.0000x reference)
//
#include <hip/hip_runtime.h>
#include <hip/hip_bf16.h>
#include <math.h>

#define DIM 256          // D_IN == EMBED == 256
#define HEADS 8
#define HEAD_DIM 32

typedef short  s16x8 __attribute__((ext_vector_type(8)));
typedef float  f32x4 __attribute__((ext_vector_type(4)));

// fp32 -> bf16 (RNE) via bit ops (no __bf16 scalar arithmetic needed)
__device__ __forceinline__ unsigned short f2bf_rne(float f) {
  unsigned int b = __builtin_bit_cast(unsigned int, f);
  b = (b + 0x7FFFu + ((b >> 16) & 1u)) >> 16;
  return (unsigned short)b;
}
__device__ __forceinline__ float bf2f(unsigned short s) {
  unsigned int b = ((unsigned int)s) << 16;
  return __builtin_bit_cast(float, b);
}

// ---------------------------------------------------------------------------
// W transpose + split-bf16 convert: Wt_hi/Wt_lo [n][k] from W [k][n] (fp32).
// Tiny (2 x 256KB); runs once per launch. Block = one output column set.
// ---------------------------------------------------------------------------
__global__ __launch_bounds__(256) void wtrans_kernel(
    const float* __restrict__ Wi, const float* __restrict__ Wj,
    short* __restrict__ Wt_ih, short* __restrict__ Wt_il,
    short* __restrict__ Wt_jh, short* __restrict__ Wt_jl) {
  const int n = blockIdx.x & 255;
  const float* W = (blockIdx.x < 256) ? Wi : Wj;
  short* Th = (blockIdx.x < 256) ? Wt_ih : Wt_jh;
  short* Tl = (blockIdx.x < 256) ? Wt_il : Wt_jl;
  const int k = threadIdx.x;
  float f = W[k * 256 + n];
  unsigned short hb = f2bf_rne(f);
  unsigned short lb = f2bf_rne(f - bf2f(hb));
  Th[n * 256 + k] = (short)hb;   // coalesced writes
  Tl[n * 256 + k] = (short)lb;
}

// ---------------------------------------------------------------------------
// Split-bf16 MFMA dual projection: Pi = nodes@Wi + bi ; Pj = nodes@Wj + bj
// Block: 512 thr (8 waves), A-tile 32 rows x K=256 staged in LDS as bf16
// hi/lo (XOR-swizzled, G4). Wave w: rows (w&1)*16, cols (w>>2... w>>1)*64.
// Per 16x16 out tile: 8 K-chunks x 3 MFMA (hh, lh, hl) ~ fp32 precision.
// ---------------------------------------------------------------------------
__global__ __launch_bounds__(512, 4) void proj2_mfma_kernel(
    const float* __restrict__ nodes,
    const short* __restrict__ Wt_ih, const short* __restrict__ Wt_il,
    const short* __restrict__ Wt_jh, const short* __restrict__ Wt_jl,
    const float* __restrict__ bi, const float* __restrict__ bj,
    float* __restrict__ Pi, float* __restrict__ Pj, int M) {
  __shared__ __align__(16) short Ah[32 * 256];  // 16 KiB
  __shared__ __align__(16) short Al[32 * 256];  // 16 KiB
  const int t = threadIdx.x;
  const int row0 = blockIdx.x * 32;

  // ---- stage A tile: fp32 global -> bf16 hi/lo LDS (swizzled) ----
  const float4* n4 = (const float4*)nodes;
  #pragma unroll
  for (int i = 0; i < 2; ++i) {
    int u = t + i * 512;            // 0..1023 : 16B chunks (8 bf16)
    int r = u >> 5;                 // row 0..31
    int q = u & 31;                 // chunk-in-row (8 elements each)
    int gr = row0 + r;
    float4 v0 = make_float4(0.f, 0.f, 0.f, 0.f), v1 = v0;
    if (gr < M) {
      v0 = n4[(size_t)gr * 64 + q * 2];
      v1 = n4[(size_t)gr * 64 + q * 2 + 1];
    }
    float fv[8] = {v0.x, v0.y, v0.z, v0.w, v1.x, v1.y, v1.z, v1.w};
    s16x8 hv, lv;
    #pragma unroll
    for (int j = 0; j < 8; ++j) {
      unsigned short hb = f2bf_rne(fv[j]);
      hv[j] = (short)hb;
      lv[j] = (short)f2bf_rne(fv[j] - bf2f(hb));
    }
    int boff = r * 512 + ((q * 16) ^ ((r & 7) << 4));  // byte offset, swizzled
    *(s16x8*)((char*)Ah + boff) = hv;
    *(s16x8*)((char*)Al + boff) = lv;
  }
  __syncthreads();

  const int lane = t & 63, w = t >> 6;
  const int rg = w & 1;            // row group (16 rows)
  const int cg = w >> 1;           // col group (64 cols)
  const int lrow = rg * 16 + (lane & 15);
  const int kq = lane >> 4;        // 0..3
  const int rowbase = lrow * 512;
  const int swz = (lrow & 7) << 4;

  // A_hi fragments register-cached (8 chunks x 8 bf16)
  s16x8 Ahf[8];
  #pragma unroll
  for (int c = 0; c < 8; ++c) {
    int boff = rowbase + ((c * 64 + kq * 16) ^ swz);
    Ahf[c] = *(const s16x8*)((const char*)Ah + boff);
  }

  #pragma unroll
  for (int pass = 0; pass < 2; ++pass) {
    const short* Wth = pass ? Wt_jh : Wt_ih;
    const short* Wtl = pass ? Wt_jl : Wt_il;
    const float* bias = pass ? bj : bi;
    float* P = pass ? Pj : Pi;

    f32x4 acc[4];
    #pragma unroll
    for (int nt = 0; nt < 4; ++nt) acc[nt] = (f32x4){0.f, 0.f, 0.f, 0.f};

    #pragma unroll
    for (int c = 0; c < 8; ++c) {
      int boff = rowbase + ((c * 64 + kq * 16) ^ swz);
      s16x8 alc = *(const s16x8*)((const char*)Al + boff);
      #pragma unroll
      for (int nt = 0; nt < 4; ++nt) {
        int col = cg * 64 + nt * 16 + (lane & 15);
        const short* wb = Wth + col * 256 + c * 32 + kq * 8;
        const short* wl = Wtl + col * 256 + c * 32 + kq * 8;
        s16x8 bh = *(const s16x8*)wb;   // L1/L2-hot, 16B
        s16x8 bl = *(const s16x8*)wl;
        acc[nt] = __builtin_amdgcn_mfma_f32_16x16x32_bf16(Ahf[c], bh, acc[nt], 0, 0, 0);
        acc[nt] = __builtin_amdgcn_mfma_f32_16x16x32_bf16(alc,    bh, acc[nt], 0, 0, 0);
        acc[nt] = __builtin_amdgcn_mfma_f32_16x16x32_bf16(Ahf[c], bl, acc[nt], 0, 0, 0);
      }
    }

    // epilogue: D frag -> global (col = lane&15, row = kq*4 + reg)
    #pragma unroll
    for (int nt = 0; nt < 4; ++nt) {
      int col = cg * 64 + nt * 16 + (lane & 15);
      float bv = bias[col];
      #pragma unroll
      for (int j = 0; j < 4; ++j) {
        int gr = row0 + rg * 16 + kq * 4 + j;
        if (gr < M) P[(size_t)gr * 256 + col] = acc[nt][j] + bv;
      }
    }
  }
}

// ---------------------------------------------------------------------------
// CSR build: histogram -> hierarchical scan (A/B/C) -> scatter
// ---------------------------------------------------------------------------
__global__ void hist_kernel(const int* __restrict__ recv, int* __restrict__ cnt,
                            int E) {
  int e = blockIdx.x * 256 + threadIdx.x;
  if (e < E) atomicAdd(&cnt[recv[e]], 1);
}

// inclusive scan of x across a 256-thread block (4 waves)
__device__ __forceinline__ int block_scan256(int x, int t, int* wsum) {
  const int lane = t & 63, wid = t >> 6;
  #pragma unroll
  for (int d = 1; d < 64; d <<= 1) {
    int y = __shfl_up(x, (unsigned)d);
    if (lane >= d) x += y;
  }
  if (lane == 63) wsum[wid] = x;
  __syncthreads();
  int add = 0;
  if (wid > 0) add += wsum[0];
  if (wid > 1) add += wsum[1];
  if (wid > 2) add += wsum[2];
  x += add;
  __syncthreads();
  return x;
}

__global__ __launch_bounds__(256) void scanA_kernel(const int* __restrict__ cnt,
                                                    int* __restrict__ offs,
                                                    int* __restrict__ bsum,
                                                    int n) {
  __shared__ int wsum[4];
  const int t = threadIdx.x;
  const int i = blockIdx.x * 256 + t;
  int x = (i < n) ? cnt[i] : 0;
  int s = block_scan256(x, t, wsum);
  if (i < n) offs[i + 1] = s;
  if (t == 255) bsum[blockIdx.x] = s;
  if (t == 0 && blockIdx.x == 0) offs[0] = 0;
}

__global__ __launch_bounds__(256) void scanB_kernel(const int* __restrict__ bsum,
                                                    int* __restrict__ bbase,
                                                    int nb) {
  __shared__ int wsum[4];
  __shared__ int carry_s;
  const int t = threadIdx.x;
  if (t == 0) carry_s = 0;
  __syncthreads();
  for (int base = 0; base < nb; base += 256) {
    int i = base + t;
    int x = (i < nb) ? bsum[i] : 0;
    int s = block_scan256(x, t, wsum);
    int c = carry_s;
    if (i < nb) bbase[i] = c + s - x;  // exclusive base
    __syncthreads();
    if (t == 255) carry_s = c + s;
    __syncthreads();
  }
}

__global__ __launch_bounds__(256) void scanC_kernel(int* __restrict__ offs,
                                                    const int* __restrict__ bbase,
                                                    int n) {
  const int i = blockIdx.x * 256 + threadIdx.x;
  if (i < n) offs[i + 1] += bbase[blockIdx.x];
}

__global__ void scatter_kernel(const int* __restrict__ recv,
                               const int* __restrict__ snd,
                               const int* __restrict__ offs,
                               int* __restrict__ cursor,
                               int* __restrict__ sorted_snd, int E) {
  int e = blockIdx.x * 256 + threadIdx.x;
  if (e < E) {
    int r = recv[e];
    int slot = offs[r] + atomicAdd(&cursor[r], 1);
    sorted_snd[slot] = snd[e];
  }
}

// ---------------------------------------------------------------------------
// Fused per-node kernel: one wave per receiver node (online softmax).
// ---------------------------------------------------------------------------
__device__ __forceinline__ float mish_f(float x) {
  float t = __expf(fminf(x, 40.f));
  float u = t * (t + 2.f);
  return x * u * __builtin_amdgcn_rcpf(u + 2.f);
}

__global__ __launch_bounds__(256) void node_kernel(
    const float* __restrict__ Pi, const float* __restrict__ Pj,
    const int* __restrict__ offs, const int* __restrict__ sorted_snd,
    const float* __restrict__ a_w, const float* __restrict__ a_b,
    float* __restrict__ out, int n) {
  const int wid = threadIdx.x >> 6, lane = threadIdx.x & 63;
  const int r = blockIdx.x * 4 + wid;
  if (r >= n) return;

  const int beg = offs[r], end = offs[r + 1];
  const float4* Pi4 = (const float4*)Pi;
  const float4* Pj4 = (const float4*)Pj;

  const float4 pj = Pj4[r * 64 + lane];
  const float4 aw = ((const float4*)a_w)[lane & 7];
  const float ab = a_b[0];

  float4 acc = make_float4(0.f, 0.f, 0.f, 0.f);
  float m = -INFINITY, denom = 0.f;

  float4 pi_next = make_float4(0.f, 0.f, 0.f, 0.f);
  if (beg < end) pi_next = Pi4[(size_t)sorted_snd[beg] * 64 + lane];

  for (int idx = beg; idx < end; ++idx) {
    float4 pi = pi_next;
    if (idx + 1 < end)
      pi_next = Pi4[(size_t)sorted_snd[idx + 1] * 64 + lane];  // prefetch

    float partial;
    partial  = mish_f(pi.x + pj.x) * aw.x;
    partial += mish_f(pi.y + pj.y) * aw.y;
    partial += mish_f(pi.z + pj.z) * aw.z;
    partial += mish_f(pi.w + pj.w) * aw.w;
    partial += __shfl_xor(partial, 1);
    partial += __shfl_xor(partial, 2);
    partial += __shfl_xor(partial, 4);

    float lo = partial + ab;
    float mn = fmaxf(m, lo);
    float scale = __expf(m - mn);
    float p = __expf(lo - mn);
    denom = denom * scale + p;
    acc.x = acc.x * scale + p * pi.x;
    acc.y = acc.y * scale + p * pi.y;
    acc.z = acc.z * scale + p * pi.z;
    acc.w = acc.w * scale + p * pi.w;
    m = mn;
  }

  float inv = (end > beg) ? 1.f / denom : 0.f;
  float4 o = make_float4(acc.x * inv, acc.y * inv, acc.z * inv, acc.w * inv);
  ((float4*)out)[r * 64 + lane] = o;
}

// ---------------------------------------------------------------------------
extern "C" void kernel_launch(void* const* d_in, const int* in_sizes, int n_in,
                              void* d_out, int out_size, void* d_ws,
                              size_t ws_size, hipStream_t stream) {
  const float* nodes = (const float*)d_in[0];
  const int* senders = (const int*)d_in[1];
  const int* receivers = (const int*)d_in[2];
  const float* Wi = (const float*)d_in[3];
  const float* bi = (const float*)d_in[4];
  const float* Wj = (const float*)d_in[5];
  const float* bj = (const float*)d_in[6];
  const float* a_w = (const float*)d_in[7];
  const float* a_b = (const float*)d_in[8];
  float* out = (float*)d_out;

  const int N = in_sizes[0] / DIM;
  const int E = in_sizes[1];
  const int nb = (N + 255) / 256;

  // workspace layout
  char* ws = (char*)d_ws;
  float* Pi = (float*)ws;                         // N*256 f32
  float* Pj = Pi + (size_t)N * DIM;               // N*256 f32
  int* cnt = (int*)(Pj + (size_t)N * DIM);        // N
  int* cursor = cnt + N;                          // N
  int* offs = cursor + N;                         // N+1
  int* bsum = offs + N + 1;                       // nb
  int* bbase = bsum + nb;                         // nb
  int* sorted_snd = bbase + nb;                   // E
  // Wt buffers ALIAS sorted_snd region: Wt is written (wtrans) and read
  // (proj) strictly before scatter writes sorted_snd. 4 x 128KB <= E*4B.
  short* Wt_ih = (short*)(((uintptr_t)sorted_snd + 15) & ~(uintptr_t)15);
  short* Wt_il = Wt_ih + 65536;
  short* Wt_jh = Wt_il + 65536;
  short* Wt_jl = Wt_jh + 65536;

  hipMemsetAsync(cnt, 0, (size_t)2 * N * sizeof(int), stream);

  wtrans_kernel<<<512, 256, 0, stream>>>(Wi, Wj, Wt_ih, Wt_il, Wt_jh, Wt_jl);
  proj2_mfma_kernel<<<(N + 31) / 32, 512, 0, stream>>>(
      nodes, Wt_ih, Wt_il, Wt_jh, Wt_jl, bi, bj, Pi, Pj, N);

  hist_kernel<<<(E + 255) / 256, 256, 0, stream>>>(receivers, cnt, E);
  scanA_kernel<<<nb, 256, 0, stream>>>(cnt, offs, bsum, N);
  scanB_kernel<<<1, 256, 0, stream>>>(bsum, bbase, nb);
  scanC_kernel<<<nb, 256, 0, stream>>>(offs, bbase, N);
  scatter_kernel<<<(E + 255) / 256, 256, 0, stream>>>(receivers, senders, offs,
                                                      cursor, sorted_snd, E);

  node_kernel<<<(N + 3) / 4, 256, 0, stream>>>(Pi, Pj, offs, sorted_snd, a_w,
                                               a_b, out, N);
}

// Round 6
// 324.612 us; speedup vs baseline: 1.3552x; 1.3552x over previous
//
#include <hip/hip_runtime.h>
#include <hip/hip_bf16.h>
#include <math.h>

#define DIM 256          // D_IN == EMBED == 256
#define HEADS 8
#define HEAD_DIM 32

typedef short  s16x8 __attribute__((ext_vector_type(8)));
typedef float  f32x4 __attribute__((ext_vector_type(4)));

// fp32 -> bf16 (RNE) via bit ops
__device__ __forceinline__ unsigned short f2bf_rne(float f) {
  unsigned int b = __builtin_bit_cast(unsigned int, f);
  b = (b + 0x7FFFu + ((b >> 16) & 1u)) >> 16;
  return (unsigned short)b;
}
__device__ __forceinline__ float bf2f(unsigned short s) {
  unsigned int b = ((unsigned int)s) << 16;
  return __builtin_bit_cast(float, b);
}

// ---------------------------------------------------------------------------
// W transpose + split-bf16 convert: Wt_hi/Wt_lo [n][k] from W [k][n] (fp32).
// ---------------------------------------------------------------------------
__global__ __launch_bounds__(256) void wtrans_kernel(
    const float* __restrict__ Wi, const float* __restrict__ Wj,
    short* __restrict__ Wt_ih, short* __restrict__ Wt_il,
    short* __restrict__ Wt_jh, short* __restrict__ Wt_jl) {
  const int n = blockIdx.x & 255;
  const float* W = (blockIdx.x < 256) ? Wi : Wj;
  short* Th = (blockIdx.x < 256) ? Wt_ih : Wt_jh;
  short* Tl = (blockIdx.x < 256) ? Wt_il : Wt_jl;
  const int k = threadIdx.x;
  float f = W[k * 256 + n];
  unsigned short hb = f2bf_rne(f);
  unsigned short lb = f2bf_rne(f - bf2f(hb));
  Th[n * 256 + k] = (short)hb;
  Tl[n * 256 + k] = (short)lb;
}

// ---------------------------------------------------------------------------
// Split-bf16 MFMA dual projection, tile M=64 x N=256 x K=256 (full-K LDS).
// Block: 256 thr (4 waves); wave w owns cols w*64..w*64+63, all 64 rows.
// LDS: A hi + lo, 64 rows x 256 k bf16, XOR-swizzled -> 64 KiB, 2 blocks/CU.
// Per k-subchunk (32): 8 B-loads feed 48 MFMAs per wave (12 per hi/lo pair).
// ---------------------------------------------------------------------------
__global__ __launch_bounds__(256, 2) void proj2_mfma_kernel(
    const float* __restrict__ nodes,
    const short* __restrict__ Wt_ih, const short* __restrict__ Wt_il,
    const short* __restrict__ Wt_jh, const short* __restrict__ Wt_jl,
    const float* __restrict__ bi, const float* __restrict__ bj,
    float* __restrict__ Pi, float* __restrict__ Pj, int M) {
  __shared__ __align__(16) short Ah[64 * 256];  // 32 KiB
  __shared__ __align__(16) short Al[64 * 256];  // 32 KiB
  const int t = threadIdx.x;
  const int row0 = blockIdx.x * 64;

  // ---- stage A: 64 rows x 256 k, fp32 -> bf16 hi/lo, swizzled ----
  const float4* n4 = (const float4*)nodes;
  #pragma unroll
  for (int i = 0; i < 16; ++i) {
    int u = t + i * 256;            // 0..4095 float4 slots
    int r = u >> 6;                 // row 0..63
    int q = u & 63;                 // float4 within row
    int gr = row0 + r;
    float4 v = make_float4(0.f, 0.f, 0.f, 0.f);
    if (gr < M) v = n4[(size_t)gr * 64 + q];
    float fv[4] = {v.x, v.y, v.z, v.w};
    short hv[4], lv[4];
    #pragma unroll
    for (int j = 0; j < 4; ++j) {
      unsigned short hb = f2bf_rne(fv[j]);
      hv[j] = (short)hb;
      lv[j] = (short)f2bf_rne(fv[j] - bf2f(hb));
    }
    int boff = r * 512 + ((q * 8) ^ ((r & 7) << 4));  // byte offset (8B, no straddle)
    *(short4*)((char*)Ah + boff) = make_short4(hv[0], hv[1], hv[2], hv[3]);
    *(short4*)((char*)Al + boff) = make_short4(lv[0], lv[1], lv[2], lv[3]);
  }
  __syncthreads();

  const int lane = t & 63, cg = t >> 6;   // wave = col group (64 cols)
  const int l15 = lane & 15;
  const int kq = lane >> 4;               // 0..3

  #pragma unroll
  for (int pass = 0; pass < 2; ++pass) {
    const short* Wth = pass ? Wt_jh : Wt_ih;
    const short* Wtl = pass ? Wt_jl : Wt_il;
    const float* bias = pass ? bj : bi;
    float* P = pass ? Pj : Pi;

    f32x4 acc[4][4];   // [mt][nt]
    #pragma unroll
    for (int mt = 0; mt < 4; ++mt)
      #pragma unroll
      for (int nt = 0; nt < 4; ++nt) acc[mt][nt] = (f32x4){0.f, 0.f, 0.f, 0.f};

    #pragma unroll
    for (int c = 0; c < 8; ++c) {         // k-subchunk of 32
      // A fragments: 4 row-tiles, hi+lo (8 x ds_read_b128)
      s16x8 Ahf[4], Alf[4];
      #pragma unroll
      for (int mt = 0; mt < 4; ++mt) {
        int lr = mt * 16 + l15;
        int boff = lr * 512 + ((c * 64 + kq * 16) ^ ((lr & 7) << 4));
        Ahf[mt] = *(const s16x8*)((const char*)Ah + boff);
        Alf[mt] = *(const s16x8*)((const char*)Al + boff);
      }
      #pragma unroll
      for (int nt = 0; nt < 4; ++nt) {
        int col = cg * 64 + nt * 16 + l15;
        const short* wb = Wth + col * 256 + c * 32 + kq * 8;
        const short* wl = Wtl + col * 256 + c * 32 + kq * 8;
        s16x8 bh = *(const s16x8*)wb;     // L2-hot 16B
        s16x8 bl = *(const s16x8*)wl;
        #pragma unroll
        for (int mt = 0; mt < 4; ++mt) {
          acc[mt][nt] = __builtin_amdgcn_mfma_f32_16x16x32_bf16(Ahf[mt], bh, acc[mt][nt], 0, 0, 0);
          acc[mt][nt] = __builtin_amdgcn_mfma_f32_16x16x32_bf16(Alf[mt], bh, acc[mt][nt], 0, 0, 0);
          acc[mt][nt] = __builtin_amdgcn_mfma_f32_16x16x32_bf16(Ahf[mt], bl, acc[mt][nt], 0, 0, 0);
        }
      }
    }

    // epilogue: D frag (col = l15, row = kq*4 + j within 16-tile)
    #pragma unroll
    for (int nt = 0; nt < 4; ++nt) {
      int col = cg * 64 + nt * 16 + l15;
      float bv = bias[col];
      #pragma unroll
      for (int mt = 0; mt < 4; ++mt) {
        #pragma unroll
        for (int j = 0; j < 4; ++j) {
          int gr = row0 + mt * 16 + kq * 4 + j;
          if (gr < M) P[(size_t)gr * 256 + col] = acc[mt][nt][j] + bv;
        }
      }
    }
  }
}

// ---------------------------------------------------------------------------
// CSR build: histogram -> hierarchical scan (A/B/C) -> scatter
// ---------------------------------------------------------------------------
__global__ void hist_kernel(const int* __restrict__ recv, int* __restrict__ cnt,
                            int E) {
  int e = blockIdx.x * 256 + threadIdx.x;
  if (e < E) atomicAdd(&cnt[recv[e]], 1);
}

__device__ __forceinline__ int block_scan256(int x, int t, int* wsum) {
  const int lane = t & 63, wid = t >> 6;
  #pragma unroll
  for (int d = 1; d < 64; d <<= 1) {
    int y = __shfl_up(x, (unsigned)d);
    if (lane >= d) x += y;
  }
  if (lane == 63) wsum[wid] = x;
  __syncthreads();
  int add = 0;
  if (wid > 0) add += wsum[0];
  if (wid > 1) add += wsum[1];
  if (wid > 2) add += wsum[2];
  x += add;
  __syncthreads();
  return x;
}

__global__ __launch_bounds__(256) void scanA_kernel(const int* __restrict__ cnt,
                                                    int* __restrict__ offs,
                                                    int* __restrict__ bsum,
                                                    int n) {
  __shared__ int wsum[4];
  const int t = threadIdx.x;
  const int i = blockIdx.x * 256 + t;
  int x = (i < n) ? cnt[i] : 0;
  int s = block_scan256(x, t, wsum);
  if (i < n) offs[i + 1] = s;
  if (t == 255) bsum[blockIdx.x] = s;
  if (t == 0 && blockIdx.x == 0) offs[0] = 0;
}

__global__ __launch_bounds__(256) void scanB_kernel(const int* __restrict__ bsum,
                                                    int* __restrict__ bbase,
                                                    int nb) {
  __shared__ int wsum[4];
  __shared__ int carry_s;
  const int t = threadIdx.x;
  if (t == 0) carry_s = 0;
  __syncthreads();
  for (int base = 0; base < nb; base += 256) {
    int i = base + t;
    int x = (i < nb) ? bsum[i] : 0;
    int s = block_scan256(x, t, wsum);
    int c = carry_s;
    if (i < nb) bbase[i] = c + s - x;
    __syncthreads();
    if (t == 255) carry_s = c + s;
    __syncthreads();
  }
}

__global__ __launch_bounds__(256) void scanC_kernel(int* __restrict__ offs,
                                                    const int* __restrict__ bbase,
                                                    int n) {
  const int i = blockIdx.x * 256 + threadIdx.x;
  if (i < n) offs[i + 1] += bbase[blockIdx.x];
}

__global__ void scatter_kernel(const int* __restrict__ recv,
                               const int* __restrict__ snd,
                               const int* __restrict__ offs,
                               int* __restrict__ cursor,
                               int* __restrict__ sorted_snd, int E) {
  int e = blockIdx.x * 256 + threadIdx.x;
  if (e < E) {
    int r = recv[e];
    int slot = offs[r] + atomicAdd(&cursor[r], 1);
    sorted_snd[slot] = snd[e];
  }
}

// ---------------------------------------------------------------------------
// Fused per-node kernel: one wave per receiver node (online softmax).
// Depth-2 prefetch on the Pi gather (two 1 KiB gathers in flight).
// ---------------------------------------------------------------------------
__device__ __forceinline__ float mish_f(float x) {
  float t = __expf(fminf(x, 40.f));
  float u = t * (t + 2.f);
  return x * u * __builtin_amdgcn_rcpf(u + 2.f);
}

__global__ __launch_bounds__(256) void node_kernel(
    const float* __restrict__ Pi, const float* __restrict__ Pj,
    const int* __restrict__ offs, const int* __restrict__ sorted_snd,
    const float* __restrict__ a_w, const float* __restrict__ a_b,
    float* __restrict__ out, int n) {
  const int wid = threadIdx.x >> 6, lane = threadIdx.x & 63;
  const int r = blockIdx.x * 4 + wid;
  if (r >= n) return;

  const int beg = offs[r], end = offs[r + 1];
  const float4* Pi4 = (const float4*)Pi;
  const float4* Pj4 = (const float4*)Pj;

  const float4 pj = Pj4[r * 64 + lane];
  const float4 aw = ((const float4*)a_w)[lane & 7];
  const float ab = a_b[0];

  float4 acc = make_float4(0.f, 0.f, 0.f, 0.f);
  float m = -INFINITY, denom = 0.f;

  float4 p0 = make_float4(0.f, 0.f, 0.f, 0.f), p1 = p0;
  if (beg < end)     p0 = Pi4[(size_t)sorted_snd[beg] * 64 + lane];
  if (beg + 1 < end) p1 = Pi4[(size_t)sorted_snd[beg + 1] * 64 + lane];

  for (int idx = beg; idx < end; ++idx) {
    float4 pi = p0;
    p0 = p1;
    if (idx + 2 < end)
      p1 = Pi4[(size_t)sorted_snd[idx + 2] * 64 + lane];  // depth-2 prefetch

    float partial;
    partial  = mish_f(pi.x + pj.x) * aw.x;
    partial += mish_f(pi.y + pj.y) * aw.y;
    partial += mish_f(pi.z + pj.z) * aw.z;
    partial += mish_f(pi.w + pj.w) * aw.w;
    partial += __shfl_xor(partial, 1);
    partial += __shfl_xor(partial, 2);
    partial += __shfl_xor(partial, 4);

    float lo = partial + ab;
    float mn = fmaxf(m, lo);
    float scale = __expf(m - mn);
    float p = __expf(lo - mn);
    denom = denom * scale + p;
    acc.x = acc.x * scale + p * pi.x;
    acc.y = acc.y * scale + p * pi.y;
    acc.z = acc.z * scale + p * pi.z;
    acc.w = acc.w * scale + p * pi.w;
    m = mn;
  }

  float inv = (end > beg) ? 1.f / denom : 0.f;
  float4 o = make_float4(acc.x * inv, acc.y * inv, acc.z * inv, acc.w * inv);
  ((float4*)out)[r * 64 + lane] = o;
}

// ---------------------------------------------------------------------------
extern "C" void kernel_launch(void* const* d_in, const int* in_sizes, int n_in,
                              void* d_out, int out_size, void* d_ws,
                              size_t ws_size, hipStream_t stream) {
  const float* nodes = (const float*)d_in[0];
  const int* senders = (const int*)d_in[1];
  const int* receivers = (const int*)d_in[2];
  const float* Wi = (const float*)d_in[3];
  const float* bi = (const float*)d_in[4];
  const float* Wj = (const float*)d_in[5];
  const float* bj = (const float*)d_in[6];
  const float* a_w = (const float*)d_in[7];
  const float* a_b = (const float*)d_in[8];
  float* out = (float*)d_out;

  const int N = in_sizes[0] / DIM;
  const int E = in_sizes[1];
  const int nb = (N + 255) / 256;

  // workspace layout
  char* ws = (char*)d_ws;
  float* Pi = (float*)ws;                         // N*256 f32
  float* Pj = Pi + (size_t)N * DIM;               // N*256 f32
  int* cnt = (int*)(Pj + (size_t)N * DIM);        // N
  int* cursor = cnt + N;                          // N
  int* offs = cursor + N;                         // N+1
  int* bsum = offs + N + 1;                       // nb
  int* bbase = bsum + nb;                         // nb
  int* sorted_snd = bbase + nb;                   // E
  // Wt buffers alias sorted_snd: written/read strictly before scatter writes.
  short* Wt_ih = (short*)(((uintptr_t)sorted_snd + 15) & ~(uintptr_t)15);
  short* Wt_il = Wt_ih + 65536;
  short* Wt_jh = Wt_il + 65536;
  short* Wt_jl = Wt_jh + 65536;

  hipMemsetAsync(cnt, 0, (size_t)2 * N * sizeof(int), stream);

  wtrans_kernel<<<512, 256, 0, stream>>>(Wi, Wj, Wt_ih, Wt_il, Wt_jh, Wt_jl);
  proj2_mfma_kernel<<<(N + 63) / 64, 256, 0, stream>>>(
      nodes, Wt_ih, Wt_il, Wt_jh, Wt_jl, bi, bj, Pi, Pj, N);

  hist_kernel<<<(E + 255) / 256, 256, 0, stream>>>(receivers, cnt, E);
  scanA_kernel<<<nb, 256, 0, stream>>>(cnt, offs, bsum, N);
  scanB_kernel<<<1, 256, 0, stream>>>(bsum, bbase, nb);
  scanC_kernel<<<nb, 256, 0, stream>>>(offs, bbase, N);
  scatter_kernel<<<(E + 255) / 256, 256, 0, stream>>>(receivers, senders, offs,
                                                      cursor, sorted_snd, E);

  node_kernel<<<(N + 3) / 4, 256, 0, stream>>>(Pi, Pj, offs, sorted_snd, a_w,
                                               a_b, out, N);
}